// Round 2
// baseline (10419.161 us; speedup 1.0000x reference)
//
#include <hip/hip_runtime.h>
#include <stdint.h>
#include <stddef.h>

// Problem constants (fixed by the reference setup_inputs)
#define TB 1024   // T (sequence length)
#define NBATCH 64 // B
#define FD 256    // F (input features)
#define UD 512    // GRU units
#define G3 1536   // 3*UD
#define OD 1024   // 2*UD output dim

// ws layout
#define WS_BAR 0                               // 2dirs x 4waves x 32blks u32 = 1KB
#define WS_H 4096
#define WS_RESID (4096 + 4 * NBATCH * UD * 2)  // after 4 h-buffers (bf16)

#define NREC 64        // recurrent blocks (32 per direction)
#define NRESID 16384   // residual GEMM tiles: (65536/64) * (1024/64)

typedef __bf16 v8bf __attribute__((ext_vector_type(8)));
typedef float v4f __attribute__((ext_vector_type(4)));

__device__ __forceinline__ v4f mfma16(v8bf a, v8bf b, v4f c) {
  return __builtin_amdgcn_mfma_f32_16x16x32_bf16(a, b, c, 0, 0, 0);
}

__device__ __forceinline__ float sigf(float x) {
  return 1.0f / (1.0f + __expf(-x));
}
__device__ __forceinline__ float tanhf_fast(float x) {
  float ax = fabsf(x);
  float e = __expf(-2.0f * ax);
  float t = (1.0f - e) / (1.0f + e);
  return copysignf(t, x);
}

// convert 8 consecutive fp32 -> bf16x8 fragment
__device__ __forceinline__ v8bf cvt8(const float* p) {
  float4 a = *(const float4*)p;
  float4 b = *(const float4*)(p + 4);
  v8bf r;
  r[0] = (__bf16)a.x; r[1] = (__bf16)a.y; r[2] = (__bf16)a.z; r[3] = (__bf16)a.w;
  r[4] = (__bf16)b.x; r[5] = (__bf16)b.y; r[6] = (__bf16)b.z; r[7] = (__bf16)b.w;
  return r;
}

struct XW { v4f a0, a1, a2; };

// x@W + bi for one timestep (per-wave 16x48 tile). Independent of h: computed
// inside the wait window. No per-step cache invalidation anymore, so x stays
// hot in L1/L2 across steps.
__device__ __forceinline__ XW compute_xw(const float* __restrict__ x,
                                         const v8bf wfr[8][3],
                                         float bi0, float bi1, float bi2,
                                         int b, int t, int quad) {
  XW r;
  r.a0 = v4f{bi0, bi0, bi0, bi0};
  r.a1 = v4f{bi1, bi1, bi1, bi1};
  r.a2 = v4f{bi2, bi2, bi2, bi2};
  const float* xp = x + ((size_t)b * TB + t) * FD + quad * 8;
#pragma unroll
  for (int ki = 0; ki < 8; ++ki) {
    v8bf xa = cvt8(xp + ki * 32);
    r.a0 = mfma16(xa, wfr[ki][0], r.a0);
    r.a1 = mfma16(xa, wfr[ki][1], r.a1);
    r.a2 = mfma16(xa, wfr[ki][2], r.a2);
  }
  return r;
}

__device__ void recurrent_body(const float* __restrict__ x,
                               const float* __restrict__ Wd,
                               const float* __restrict__ Ud,
                               const float* __restrict__ bd,
                               float* __restrict__ out,
                               char* __restrict__ ws, int bx) {
  const int dir = bx >> 5;           // 0 = forward, 1 = backward
  const int blk = bx & 31;
  const int j0 = blk * 16;           // this block's 16 h-columns
  const int tid = threadIdx.x;
  const int lane = tid & 63;
  const int col16 = lane & 15;
  const int quad = lane >> 4;
  const int wave = tid >> 6;
  const int m0 = wave * 16;          // wave's m-tile (batch rows)

  // Per-(dir,wave) flag group: flagsW[blk] = #steps published by wave `wave`
  // of block blk (rows [16*wave, 16*wave+16)). Consumer wave w only needs the
  // h-rows produced by its 32 row-peer waves -> polls exactly this group.
  // All flag/h traffic is agent-scope RELAXED atomic = sc0|sc1 L2-bypass to
  // the coherence point (L3). NO fences anywhere in the loop: no buffer_wbl2,
  // no L2 invalidate (the round-0/1 per-step cost).
  uint32_t* flagsW = (uint32_t*)(ws + WS_BAR) + (dir * 4 + wave) * 32;
  __bf16* h0 = (__bf16*)(ws + WS_H) + (size_t)dir * 2 * NBATCH * UD;
  __bf16* h1 = h0 + NBATCH * UD;

  // ---- persistent U fragments in registers: B[k][n], n=lane&15, k=quad*8+e
  v8bf ufr[16][3];
#pragma unroll
  for (int ki = 0; ki < 16; ++ki) {
#pragma unroll
    for (int g = 0; g < 3; ++g) {
      const float* p = Ud + (size_t)(ki * 32 + quad * 8) * G3 + g * UD + j0 + col16;
      v8bf v;
#pragma unroll
      for (int e = 0; e < 8; ++e) v[e] = (__bf16)p[(size_t)e * G3];
      ufr[ki][g] = v;
    }
  }
  // ---- persistent W fragments (K=256 -> 8 k-iters)
  v8bf wfr[8][3];
#pragma unroll
  for (int ki = 0; ki < 8; ++ki) {
#pragma unroll
    for (int g = 0; g < 3; ++g) {
      const float* p = Wd + (size_t)(ki * 32 + quad * 8) * G3 + g * UD + j0 + col16;
      v8bf v;
#pragma unroll
      for (int e = 0; e < 8; ++e) v[e] = (__bf16)p[(size_t)e * G3];
      wfr[ki][g] = v;
    }
  }
  // biases: bd[0] = input bias bi, bd[1] = recurrent bias br
  const float bi0 = bd[0 * UD + j0 + col16];
  const float bi1 = bd[1 * UD + j0 + col16];
  const float bi2 = bd[2 * UD + j0 + col16];
  const float br0 = bd[G3 + 0 * UD + j0 + col16];
  const float br1 = bd[G3 + 1 * UD + j0 + col16];
  const float br2 = bd[G3 + 2 * UD + j0 + col16];

  const int tstep = dir ? -1 : 1;
  int t = dir ? (TB - 1) : 0;
  XW cur = compute_xw(x, wfr, bi0, bi1, bi2, m0 + col16, t, quad);

  // each lane's own h element for next step, carried in registers (the lane
  // that computes h[brow][j0+col16] is the lane that needs it as `hold`).
  float hold[4] = {0.f, 0.f, 0.f, 0.f};

  int p = 0;
  for (int s = 0; s < TB; ++s) {
    const __bf16* hcur = (p == 0) ? h0 : h1;
    __bf16* hnxt = (p == 0) ? h1 : h0;

    v4f au0 = v4f{br0, br0, br0, br0};
    v4f au1 = v4f{br1, br1, br1, br1};
    v4f au2 = v4f{br2, br2, br2, br2};
    if (s > 0) {
      // h loads via L2-bypass atomic loads (b64 x2 per fragment): always
      // fresh from the coherence point, no invalidate needed.
      const __bf16* hrow = hcur + (size_t)(m0 + col16) * UD + quad * 8;
#pragma unroll
      for (int ki = 0; ki < 16; ++ki) {
        const unsigned long long* hp =
            (const unsigned long long*)(hrow + (size_t)ki * 32);
        unsigned long long d0 = __hip_atomic_load(hp, __ATOMIC_RELAXED,
                                                  __HIP_MEMORY_SCOPE_AGENT);
        unsigned long long d1 = __hip_atomic_load(hp + 1, __ATOMIC_RELAXED,
                                                  __HIP_MEMORY_SCOPE_AGENT);
        union { unsigned long long q[2]; v8bf v; } u;
        u.q[0] = d0;
        u.q[1] = d1;
        au0 = mfma16(u.v, ufr[ki][0], au0);
        au1 = mfma16(u.v, ufr[ki][1], au1);
        au2 = mfma16(u.v, ufr[ki][2], au2);
      }
    }

    // gates (C/D layout: col = lane&15, row = quad*4 + r)
    float hn[4];
#pragma unroll
    for (int r = 0; r < 4; ++r) {
      float z = sigf(cur.a0[r] + au0[r]);
      float rg = sigf(cur.a1[r] + au1[r]);
      float hh = tanhf_fast(cur.a2[r] + rg * au2[r]);
      float v = z * hold[r] + (1.0f - z) * hh;
      hn[r] = v;
      hold[r] = v;
    }
    const int tcur = t;

    if (s < TB - 1) {
      // publish h_{s+1}: L2-bypass relaxed atomic stores straight to L3
#pragma unroll
      for (int r = 0; r < 4; ++r) {
        __bf16 hb = (__bf16)hn[r];
        unsigned short bits = __builtin_bit_cast(unsigned short, hb);
        __hip_atomic_store(
            (unsigned short*)&hnxt[(size_t)(m0 + quad * 4 + r) * UD + j0 + col16],
            bits, __ATOMIC_RELAXED, __HIP_MEMORY_SCOPE_AGENT);
      }
      // order h stores before the flag store: drain this wave's vmem. All
      // bypass stores are at the coherence point once retired -> no wbl2.
      asm volatile("s_waitcnt vmcnt(0)" ::: "memory");
      if (lane == 0) {
        __hip_atomic_store(&flagsW[blk], (uint32_t)(s + 1), __ATOMIC_RELAXED,
                           __HIP_MEMORY_SCOPE_AGENT);
      }
      // ---- wait window: overlaps peers' arrival ----
      // deferred out stores for step tcur (fire-and-forget; retired long
      // before next step's vmcnt(0))
#pragma unroll
      for (int r = 0; r < 4; ++r) {
        const int brow = m0 + quad * 4 + r;
        __builtin_nontemporal_store(
            hn[r], out + ((size_t)brow * TB + tcur) * OD + dir * UD + j0 + col16);
      }
      // prefetch next timestep's x@W (x is L1/L2-hot now)
      t += tstep;
      XW nxt = compute_xw(x, wfr, bi0, bi1, bi2, m0 + col16, t, quad);

      // poll the 32 row-peer producer waves (relaxed bypass loads). A peer's
      // flag==s+1 data-depends on its completed reads of h_s, so buffer reuse
      // is race-free; no acquire fence needed since h reads also bypass L1/L2.
      const uint32_t target = (uint32_t)(s + 1);
      for (;;) {
        uint32_t f = __hip_atomic_load(&flagsW[lane & 31], __ATOMIC_RELAXED,
                                       __HIP_MEMORY_SCOPE_AGENT);
        if (__ballot(f >= target) == ~0ull) break;
      }

      cur = nxt;
      p ^= 1;
    } else {
      // last step: just emit outputs
#pragma unroll
      for (int r = 0; r < 4; ++r) {
        const int brow = m0 + quad * 4 + r;
        __builtin_nontemporal_store(
            hn[r], out + ((size_t)brow * TB + tcur) * OD + dir * UD + j0 + col16);
      }
    }
  }
}

// residual = x @ Wp, bf16 out. Runs on the CUs the recurrence doesn't use.
__device__ void resid_body(const float* __restrict__ x,
                           const float* __restrict__ Wp,
                           __bf16* __restrict__ resid, int rb) {
  const int mb = rb & 1023;
  const int nb = rb >> 10;
  const int tid = threadIdx.x;
  const int lane = tid & 63;
  const int col16 = lane & 15;
  const int quad = lane >> 4;
  const int wave = tid >> 6;
  const int wm = wave & 1;
  const int wn = wave >> 1;
  const int rowbase = mb * 64 + wm * 32;
  const int colbase = nb * 64 + wn * 32;

  v4f acc[2][2];
#pragma unroll
  for (int i = 0; i < 2; ++i)
#pragma unroll
    for (int j = 0; j < 2; ++j) acc[i][j] = v4f{0.f, 0.f, 0.f, 0.f};

#pragma unroll
  for (int ki = 0; ki < 8; ++ki) {
    v8bf a0 = cvt8(x + (size_t)(rowbase + col16) * FD + ki * 32 + quad * 8);
    v8bf a1 = cvt8(x + (size_t)(rowbase + 16 + col16) * FD + ki * 32 + quad * 8);
    v8bf b0, b1;
#pragma unroll
    for (int e = 0; e < 8; ++e) {
      const float* wp = Wp + (size_t)(ki * 32 + quad * 8 + e) * OD + colbase + col16;
      b0[e] = (__bf16)wp[0];
      b1[e] = (__bf16)wp[16];
    }
    acc[0][0] = mfma16(a0, b0, acc[0][0]);
    acc[0][1] = mfma16(a0, b1, acc[0][1]);
    acc[1][0] = mfma16(a1, b0, acc[1][0]);
    acc[1][1] = mfma16(a1, b1, acc[1][1]);
  }
#pragma unroll
  for (int mt = 0; mt < 2; ++mt)
#pragma unroll
    for (int nt = 0; nt < 2; ++nt)
#pragma unroll
      for (int r = 0; r < 4; ++r) {
        __builtin_nontemporal_store(
            (__bf16)acc[mt][nt][r],
            resid + (size_t)(rowbase + mt * 16 + quad * 4 + r) * OD + colbase +
                nt * 16 + col16);
      }
}

__global__ __launch_bounds__(256, 1) void mega_kernel(
    const float* __restrict__ x, const float* __restrict__ Wf,
    const float* __restrict__ Uf, const float* __restrict__ bf_,
    const float* __restrict__ Wb, const float* __restrict__ Ub,
    const float* __restrict__ bb_, const float* __restrict__ Wp,
    float* __restrict__ out, char* __restrict__ ws) {
  const int bx = blockIdx.x;
  if (bx < NREC) {
    const int dir = bx >> 5;
    recurrent_body(x, dir ? Wb : Wf, dir ? Ub : Uf, dir ? bb_ : bf_, out, ws, bx);
  } else {
    resid_body(x, Wp, (__bf16*)(ws + WS_RESID), bx - NREC);
  }
}

// y = gru_out + residual; LayerNorm over last dim (1024), eps=1e-3.
// One wave per row; gru_out already sits in `out` (fp32), overwritten in place.
__global__ __launch_bounds__(256) void ln_kernel(
    const __bf16* __restrict__ resid, const float* __restrict__ gamma,
    const float* __restrict__ beta, float* __restrict__ out) {
  const int row = blockIdx.x * 4 + (threadIdx.x >> 6);
  const int lane = threadIdx.x & 63;
  const float* orow = out + (size_t)row * OD;
  const __bf16* rrow = resid + (size_t)row * OD;

  float y[16];
  float s = 0.f, s2 = 0.f;
#pragma unroll
  for (int i = 0; i < 16; ++i) {
    const int c = lane + 64 * i;
    float v = orow[c] + (float)rrow[c];
    y[i] = v;
    s += v;
    s2 += v * v;
  }
#pragma unroll
  for (int m = 32; m >= 1; m >>= 1) {
    s += __shfl_xor(s, m);
    s2 += __shfl_xor(s2, m);
  }
  const float mu = s * (1.0f / OD);
  const float var = s2 * (1.0f / OD) - mu * mu;
  const float rstd = rsqrtf(var + 1e-3f);
  float* wrow = out + (size_t)row * OD;
#pragma unroll
  for (int i = 0; i < 16; ++i) {
    const int c = lane + 64 * i;
    __builtin_nontemporal_store(gamma[c] * (y[i] - mu) * rstd + beta[c], wrow + c);
  }
}

extern "C" void kernel_launch(void* const* d_in, const int* in_sizes, int n_in,
                              void* d_out, int out_size, void* d_ws,
                              size_t ws_size, hipStream_t stream) {
  const float* x = (const float*)d_in[0];
  const float* Wf = (const float*)d_in[1];
  const float* Uf = (const float*)d_in[2];
  const float* bf_ = (const float*)d_in[3];
  const float* Wb = (const float*)d_in[4];
  const float* Ub = (const float*)d_in[5];
  const float* bb_ = (const float*)d_in[6];
  const float* Wp = (const float*)d_in[7];
  const float* gamma = (const float*)d_in[8];
  const float* beta = (const float*)d_in[9];
  float* out = (float*)d_out;
  char* ws = (char*)d_ws;

  // zero the flag arrays (ws is poisoned 0xAA before every launch)
  hipMemsetAsync(ws, 0, 2048, stream);

  // recurrence (blocks 0..63) + residual GEMM (blocks 64..) in one launch:
  // residual tiles fill the CUs the persistent recurrence doesn't occupy.
  mega_kernel<<<dim3(NREC + NRESID), dim3(256), 0, stream>>>(
      x, Wf, Uf, bf_, Wb, Ub, bb_, Wp, out, ws);

  // fused add + LayerNorm
  ln_kernel<<<dim3(65536 / 4), dim3(256), 0, stream>>>(
      (const __bf16*)(ws + WS_RESID), gamma, beta, out);
}

// Round 3
// 8730.429 us; speedup vs baseline: 1.1934x; 1.1934x over previous
//
#include <hip/hip_runtime.h>
#include <stdint.h>
#include <stddef.h>

// Problem constants (fixed by the reference setup_inputs)
#define TB 1024   // T (sequence length)
#define NBATCH 64 // B
#define FD 256    // F (input features)
#define UD 512    // GRU units
#define G3 1536   // 3*UD
#define OD 1024   // 2*UD output dim

// ws layout
#define WS_BAR 0                               // 2dirs x 4waves x 32blks u32 = 1KB
#define WS_H 4096
#define WS_RESID (4096 + 4 * NBATCH * UD * 2)  // after 4 h-buffers (bf16)

#define NREC 64        // recurrent blocks (32 per direction)
#define NRESID 16384   // residual GEMM tiles: (65536/64) * (1024/64)

// LDS layout (per recurrent block): fragment-ordered U then W, bf16.
// frag(ki,g) for lane l lives at ((ki*3+g)*64 + l)*16 bytes.
#define LDS_U 0
#define LDS_W 49152            // 16 ki * 3 g * 64 lanes * 16B = 48 KB
#define LDS_TOTAL 73728        // + 8 ki * 3 g * 64 * 16B = 24 KB

typedef __bf16 v8bf __attribute__((ext_vector_type(8)));
typedef float v4f __attribute__((ext_vector_type(4)));

__device__ __forceinline__ v4f mfma16(v8bf a, v8bf b, v4f c) {
  return __builtin_amdgcn_mfma_f32_16x16x32_bf16(a, b, c, 0, 0, 0);
}

__device__ __forceinline__ float sigf(float x) {
  return 1.0f / (1.0f + __expf(-x));
}
__device__ __forceinline__ float tanhf_fast(float x) {
  float ax = fabsf(x);
  float e = __expf(-2.0f * ax);
  float t = (1.0f - e) / (1.0f + e);
  return copysignf(t, x);
}

// convert 8 consecutive fp32 -> bf16x8 fragment
__device__ __forceinline__ v8bf cvt8(const float* p) {
  float4 a = *(const float4*)p;
  float4 b = *(const float4*)(p + 4);
  v8bf r;
  r[0] = (__bf16)a.x; r[1] = (__bf16)a.y; r[2] = (__bf16)a.z; r[3] = (__bf16)a.w;
  r[4] = (__bf16)b.x; r[5] = (__bf16)b.y; r[6] = (__bf16)b.z; r[7] = (__bf16)b.w;
  return r;
}

struct XW { v4f a0, a1, a2; };

// x@W + bi for one timestep (per-wave 16x48 tile). W fragments come from LDS
// (ds_read_b128 at lane*16 — full-throughput pattern), so no spill reloads.
__device__ __forceinline__ XW compute_xw(const float* __restrict__ x,
                                         const char* __restrict__ ldsW,
                                         float bi0, float bi1, float bi2,
                                         int b, int t, int quad, int lane) {
  XW r;
  r.a0 = v4f{bi0, bi0, bi0, bi0};
  r.a1 = v4f{bi1, bi1, bi1, bi1};
  r.a2 = v4f{bi2, bi2, bi2, bi2};
  const float* xp = x + ((size_t)b * TB + t) * FD + quad * 8;
#pragma unroll
  for (int ki = 0; ki < 8; ++ki) {
    v8bf xa = cvt8(xp + ki * 32);
    v8bf w0 = *(const v8bf*)(ldsW + ((ki * 3 + 0) * 64 + lane) * 16);
    v8bf w1 = *(const v8bf*)(ldsW + ((ki * 3 + 1) * 64 + lane) * 16);
    v8bf w2 = *(const v8bf*)(ldsW + ((ki * 3 + 2) * 64 + lane) * 16);
    r.a0 = mfma16(xa, w0, r.a0);
    r.a1 = mfma16(xa, w1, r.a1);
    r.a2 = mfma16(xa, w2, r.a2);
  }
  return r;
}

__device__ void recurrent_body(const float* __restrict__ x,
                               const float* __restrict__ Wd,
                               const float* __restrict__ Ud,
                               const float* __restrict__ bd,
                               float* __restrict__ out,
                               char* __restrict__ ws,
                               char* __restrict__ smem, int bx) {
  const int dir = bx >> 5;           // 0 = forward, 1 = backward
  const int blk = bx & 31;
  const int j0 = blk * 16;           // this block's 16 h-columns
  const int tid = threadIdx.x;
  const int lane = tid & 63;
  const int col16 = lane & 15;
  const int quad = lane >> 4;
  const int wave = tid >> 6;
  const int m0 = wave * 16;          // wave's m-tile (batch rows)

  uint32_t* flagsW = (uint32_t*)(ws + WS_BAR) + (dir * 4 + wave) * 32;
  __bf16* h0 = (__bf16*)(ws + WS_H) + (size_t)dir * 2 * NBATCH * UD;
  __bf16* h1 = h0 + NBATCH * UD;

  // ---- stage U fragments into LDS (bf16, fragment order). The previous
  // version kept ufr[16][3] (192 VGPR) + wfr[8][3] (96 VGPR) in "registers":
  // 330+ VGPRs needed vs 220 allocated -> spilled to scratch, and the per-step
  // spill-reload chain (~70 L2 round trips serialized with MFMAs) was the
  // hidden ~8 us/step floor that made every sync change neutral.
  char* ldsU = smem + LDS_U;
  char* ldsW = smem + LDS_W;
#pragma unroll
  for (int kk = 0; kk < 4; ++kk) {
    const int ki = wave + kk * 4;    // 4 waves cover ki = 0..15
#pragma unroll
    for (int g = 0; g < 3; ++g) {
      const float* p = Ud + (size_t)(ki * 32 + quad * 8) * G3 + g * UD + j0 + col16;
      v8bf v;
#pragma unroll
      for (int e = 0; e < 8; ++e) v[e] = (__bf16)p[(size_t)e * G3];
      *(v8bf*)(ldsU + ((ki * 3 + g) * 64 + lane) * 16) = v;
    }
  }
#pragma unroll
  for (int kk = 0; kk < 2; ++kk) {
    const int ki = wave + kk * 4;    // 4 waves cover ki = 0..7
#pragma unroll
    for (int g = 0; g < 3; ++g) {
      const float* p = Wd + (size_t)(ki * 32 + quad * 8) * G3 + g * UD + j0 + col16;
      v8bf v;
#pragma unroll
      for (int e = 0; e < 8; ++e) v[e] = (__bf16)p[(size_t)e * G3];
      *(v8bf*)(ldsW + ((ki * 3 + g) * 64 + lane) * 16) = v;
    }
  }
  // biases: bd[0] = input bias bi, bd[1] = recurrent bias br
  const float bi0 = bd[0 * UD + j0 + col16];
  const float bi1 = bd[1 * UD + j0 + col16];
  const float bi2 = bd[2 * UD + j0 + col16];
  const float br0 = bd[G3 + 0 * UD + j0 + col16];
  const float br1 = bd[G3 + 1 * UD + j0 + col16];
  const float br2 = bd[G3 + 2 * UD + j0 + col16];
  __syncthreads();  // LDS fragments visible to all waves

  const int tstep = dir ? -1 : 1;
  int t = dir ? (TB - 1) : 0;
  XW cur = compute_xw(x, ldsW, bi0, bi1, bi2, m0 + col16, t, quad, lane);

  // each lane's own h element for next step, carried in registers
  float hold[4] = {0.f, 0.f, 0.f, 0.f};

  int p = 0;
  for (int s = 0; s < TB; ++s) {
    const __bf16* hcur = (p == 0) ? h0 : h1;
    __bf16* hnxt = (p == 0) ? h1 : h0;

    v4f au0 = v4f{br0, br0, br0, br0};
    v4f au1 = v4f{br1, br1, br1, br1};
    v4f au2 = v4f{br2, br2, br2, br2};
    if (s > 0) {
      // h loads via L2-bypass atomic loads; U fragments stream from LDS.
      const __bf16* hrow = hcur + (size_t)(m0 + col16) * UD + quad * 8;
#pragma unroll
      for (int ki = 0; ki < 16; ++ki) {
        const unsigned long long* hp =
            (const unsigned long long*)(hrow + (size_t)ki * 32);
        unsigned long long d0 = __hip_atomic_load(hp, __ATOMIC_RELAXED,
                                                  __HIP_MEMORY_SCOPE_AGENT);
        unsigned long long d1 = __hip_atomic_load(hp + 1, __ATOMIC_RELAXED,
                                                  __HIP_MEMORY_SCOPE_AGENT);
        union { unsigned long long q[2]; v8bf v; } u;
        u.q[0] = d0;
        u.q[1] = d1;
        v8bf u0 = *(const v8bf*)(ldsU + ((ki * 3 + 0) * 64 + lane) * 16);
        v8bf u1 = *(const v8bf*)(ldsU + ((ki * 3 + 1) * 64 + lane) * 16);
        v8bf u2 = *(const v8bf*)(ldsU + ((ki * 3 + 2) * 64 + lane) * 16);
        au0 = mfma16(u.v, u0, au0);
        au1 = mfma16(u.v, u1, au1);
        au2 = mfma16(u.v, u2, au2);
      }
    }

    // gates (C/D layout: col = lane&15, row = quad*4 + r)
    float hn[4];
#pragma unroll
    for (int r = 0; r < 4; ++r) {
      float z = sigf(cur.a0[r] + au0[r]);
      float rg = sigf(cur.a1[r] + au1[r]);
      float hh = tanhf_fast(cur.a2[r] + rg * au2[r]);
      float v = z * hold[r] + (1.0f - z) * hh;
      hn[r] = v;
      hold[r] = v;
    }
    const int tcur = t;

    if (s < TB - 1) {
      // publish h_{s+1}: L2-bypass relaxed atomic stores straight to L3
#pragma unroll
      for (int r = 0; r < 4; ++r) {
        __bf16 hb = (__bf16)hn[r];
        unsigned short bits = __builtin_bit_cast(unsigned short, hb);
        __hip_atomic_store(
            (unsigned short*)&hnxt[(size_t)(m0 + quad * 4 + r) * UD + j0 + col16],
            bits, __ATOMIC_RELAXED, __HIP_MEMORY_SCOPE_AGENT);
      }
      // order h stores before the flag store
      asm volatile("s_waitcnt vmcnt(0)" ::: "memory");
      if (lane == 0) {
        __hip_atomic_store(&flagsW[blk], (uint32_t)(s + 1), __ATOMIC_RELAXED,
                           __HIP_MEMORY_SCOPE_AGENT);
      }
      // ---- wait window: overlaps peers' arrival ----
#pragma unroll
      for (int r = 0; r < 4; ++r) {
        const int brow = m0 + quad * 4 + r;
        __builtin_nontemporal_store(
            hn[r], out + ((size_t)brow * TB + tcur) * OD + dir * UD + j0 + col16);
      }
      // prefetch next timestep's x@W
      t += tstep;
      XW nxt = compute_xw(x, ldsW, bi0, bi1, bi2, m0 + col16, t, quad, lane);

      // poll the 32 row-peer producer waves (relaxed bypass loads)
      const uint32_t target = (uint32_t)(s + 1);
      for (;;) {
        uint32_t f = __hip_atomic_load(&flagsW[lane & 31], __ATOMIC_RELAXED,
                                       __HIP_MEMORY_SCOPE_AGENT);
        if (__ballot(f >= target) == ~0ull) break;
      }

      cur = nxt;
      p ^= 1;
    } else {
      // last step: just emit outputs
#pragma unroll
      for (int r = 0; r < 4; ++r) {
        const int brow = m0 + quad * 4 + r;
        __builtin_nontemporal_store(
            hn[r], out + ((size_t)brow * TB + tcur) * OD + dir * UD + j0 + col16);
      }
    }
  }
}

// residual = x @ Wp, bf16 out. Runs on the CUs the recurrence doesn't use.
__device__ void resid_body(const float* __restrict__ x,
                           const float* __restrict__ Wp,
                           __bf16* __restrict__ resid, int rb) {
  const int mb = rb & 1023;
  const int nb = rb >> 10;
  const int tid = threadIdx.x;
  const int lane = tid & 63;
  const int col16 = lane & 15;
  const int quad = lane >> 4;
  const int wave = tid >> 6;
  const int wm = wave & 1;
  const int wn = wave >> 1;
  const int rowbase = mb * 64 + wm * 32;
  const int colbase = nb * 64 + wn * 32;

  v4f acc[2][2];
#pragma unroll
  for (int i = 0; i < 2; ++i)
#pragma unroll
    for (int j = 0; j < 2; ++j) acc[i][j] = v4f{0.f, 0.f, 0.f, 0.f};

#pragma unroll
  for (int ki = 0; ki < 8; ++ki) {
    v8bf a0 = cvt8(x + (size_t)(rowbase + col16) * FD + ki * 32 + quad * 8);
    v8bf a1 = cvt8(x + (size_t)(rowbase + 16 + col16) * FD + ki * 32 + quad * 8);
    v8bf b0, b1;
#pragma unroll
    for (int e = 0; e < 8; ++e) {
      const float* wp = Wp + (size_t)(ki * 32 + quad * 8 + e) * OD + colbase + col16;
      b0[e] = (__bf16)wp[0];
      b1[e] = (__bf16)wp[16];
    }
    acc[0][0] = mfma16(a0, b0, acc[0][0]);
    acc[0][1] = mfma16(a0, b1, acc[0][1]);
    acc[1][0] = mfma16(a1, b0, acc[1][0]);
    acc[1][1] = mfma16(a1, b1, acc[1][1]);
  }
#pragma unroll
  for (int mt = 0; mt < 2; ++mt)
#pragma unroll
    for (int nt = 0; nt < 2; ++nt)
#pragma unroll
      for (int r = 0; r < 4; ++r) {
        __builtin_nontemporal_store(
            (__bf16)acc[mt][nt][r],
            resid + (size_t)(rowbase + mt * 16 + quad * 4 + r) * OD + colbase +
                nt * 16 + col16);
      }
}

__global__ __launch_bounds__(256, 1) void mega_kernel(
    const float* __restrict__ x, const float* __restrict__ Wf,
    const float* __restrict__ Uf, const float* __restrict__ bf_,
    const float* __restrict__ Wb, const float* __restrict__ Ub,
    const float* __restrict__ bb_, const float* __restrict__ Wp,
    float* __restrict__ out, char* __restrict__ ws) {
  __shared__ __align__(16) char smem[LDS_TOTAL];
  const int bx = blockIdx.x;
  if (bx < NREC) {
    const int dir = bx >> 5;
    recurrent_body(x, dir ? Wb : Wf, dir ? Ub : Uf, dir ? bb_ : bf_, out, ws,
                   smem, bx);
  } else {
    resid_body(x, Wp, (__bf16*)(ws + WS_RESID), bx - NREC);
  }
}

// y = gru_out + residual; LayerNorm over last dim (1024), eps=1e-3.
// One wave per row; gru_out already sits in `out` (fp32), overwritten in place.
__global__ __launch_bounds__(256) void ln_kernel(
    const __bf16* __restrict__ resid, const float* __restrict__ gamma,
    const float* __restrict__ beta, float* __restrict__ out) {
  const int row = blockIdx.x * 4 + (threadIdx.x >> 6);
  const int lane = threadIdx.x & 63;
  const float* orow = out + (size_t)row * OD;
  const __bf16* rrow = resid + (size_t)row * OD;

  float y[16];
  float s = 0.f, s2 = 0.f;
#pragma unroll
  for (int i = 0; i < 16; ++i) {
    const int c = lane + 64 * i;
    float v = orow[c] + (float)rrow[c];
    y[i] = v;
    s += v;
    s2 += v * v;
  }
#pragma unroll
  for (int m = 32; m >= 1; m >>= 1) {
    s += __shfl_xor(s, m);
    s2 += __shfl_xor(s2, m);
  }
  const float mu = s * (1.0f / OD);
  const float var = s2 * (1.0f / OD) - mu * mu;
  const float rstd = rsqrtf(var + 1e-3f);
  float* wrow = out + (size_t)row * OD;
#pragma unroll
  for (int i = 0; i < 16; ++i) {
    const int c = lane + 64 * i;
    __builtin_nontemporal_store(gamma[c] * (y[i] - mu) * rstd + beta[c], wrow + c);
  }
}

extern "C" void kernel_launch(void* const* d_in, const int* in_sizes, int n_in,
                              void* d_out, int out_size, void* d_ws,
                              size_t ws_size, hipStream_t stream) {
  const float* x = (const float*)d_in[0];
  const float* Wf = (const float*)d_in[1];
  const float* Uf = (const float*)d_in[2];
  const float* bf_ = (const float*)d_in[3];
  const float* Wb = (const float*)d_in[4];
  const float* Ub = (const float*)d_in[5];
  const float* bb_ = (const float*)d_in[6];
  const float* Wp = (const float*)d_in[7];
  const float* gamma = (const float*)d_in[8];
  const float* beta = (const float*)d_in[9];
  float* out = (float*)d_out;
  char* ws = (char*)d_ws;

  // zero the flag arrays (ws is poisoned 0xAA before every launch)
  hipMemsetAsync(ws, 0, 2048, stream);

  // recurrence (blocks 0..63) + residual GEMM (blocks 64..) in one launch
  mega_kernel<<<dim3(NREC + NRESID), dim3(256), 0, stream>>>(
      x, Wf, Uf, bf_, Wb, Ub, bb_, Wp, out, ws);

  // fused add + LayerNorm
  ln_kernel<<<dim3(65536 / 4), dim3(256), 0, stream>>>(
      (const __bf16*)(ws + WS_RESID), gamma, beta, out);
}